// Round 13
// baseline (119.824 us; speedup 1.0000x reference)
//
#include <hip/hip_runtime.h>

// ---------------------------------------------------------------------------
// SelfAttention with QA-LoRA quantized projections, MI355X (gfx950)
// Round 13: 2-way split-K attention (m=0 makes partials exactly additive):
//           grid 1024 -> 4 blocks/CU (16 waves/CU, was 8). kh=0 partial in
//           attnb (bf16, unnormalized), kh=1 in pbuf; f32 denominators;
//           k_merge normalizes + head-means + pad. Prep kernels fused into
//           one launch. GEMMs identical to round 12.
// ---------------------------------------------------------------------------

typedef __bf16 bf16x8 __attribute__((ext_vector_type(8)));
typedef float f32x4 __attribute__((ext_vector_type(4)));

#define MFMA(a, b, c) __builtin_amdgcn_mfma_f32_16x16x32_bf16(a, b, c, 0, 0, 0)

#define KEXT 1088   // 1024 + 64 extension cols (16 LoRA + 48 zeros)

__device__ __forceinline__ void gld16(const void* g, void* l) {
  __builtin_amdgcn_global_load_lds(
      (const __attribute__((address_space(1))) void*)g,
      (__attribute__((address_space(3))) void*)l, 16, 0, 0);
}

// fake_quantize: returns the clipped, round-half-even INTEGER (not dequantized).
__device__ __forceinline__ float fq(float v) {
  float q = rintf(v / 0.1f);           // v_rndne_f32: round half to even
  return fminf(fmaxf(q, -128.f), 127.f);
}

__device__ __forceinline__ float redsum16(float v) {
  v += __shfl_xor(v, 1);
  v += __shfl_xor(v, 2);
  v += __shfl_xor(v, 4);
  v += __shfl_xor(v, 8);
  return v;
}

// ---------------- fused prep kernel ----------------
// blocks 0..4095: weights -> bf16 int codes (stride-1088)
// blocks 4096..8191: x -> bf16 + ext-col group means
// blocks 8192..8447: LoRA delta -> ext cols of wq
__global__ __launch_bounds__(256) void k_prep(
    const float* __restrict__ x,
    const float* __restrict__ w0, const float* __restrict__ w1,
    const float* __restrict__ w2, const float* __restrict__ w3,
    const float* __restrict__ dW0, const float* __restrict__ dB0,
    const float* __restrict__ dW1, const float* __restrict__ dB1,
    const float* __restrict__ dW2, const float* __restrict__ dB2,
    const float* __restrict__ dW3, const float* __restrict__ dB3,
    __bf16* __restrict__ wq, __bf16* __restrict__ xbf) {
  int blk = blockIdx.x, t = threadIdx.x;
  if (blk < 4096) {
    int i = blk * 256 + t;
    int layer = i >> 18, rest = i & 262143;
    int o = rest >> 8, c4 = rest & 255;
    const float* src = (layer == 0) ? w0 : (layer == 1) ? w1 : (layer == 2) ? w2 : w3;
    float4 v = ((const float4*)src)[rest];
    __bf16 r[4] = {(__bf16)fq(v.x), (__bf16)fq(v.y), (__bf16)fq(v.z), (__bf16)fq(v.w)};
    *(uint2*)(wq + (size_t)((layer << 10) | o) * KEXT + (c4 << 2)) = *(uint2*)r;
  } else if (blk < 8192) {
    int row = blk - 4096;
    float4 v = ((const float4*)(x + (size_t)row * 1024))[t];
    __bf16 r[4] = {(__bf16)v.x, (__bf16)v.y, (__bf16)v.z, (__bf16)v.w};
    *(uint2*)(xbf + (size_t)row * KEXT + 4 * t) = *(uint2*)r;
    float s = v.x + v.y + v.z + v.w;
    s = redsum16(s);
    int g = t >> 4, j = t & 15;
    __bf16* ext = xbf + (size_t)row * KEXT + 1024;
    if (j == 0) ext[g] = (__bf16)(s * (1.f / 64.f));
    else if (j < 4) ext[16 + g * 3 + (j - 1)] = (__bf16)0.f;
  } else {
    int i = (blk - 8192) * 256 + t;
    int layer = i >> 14, o = (i >> 4) & 1023, g = i & 15;
    const float* dW = (layer == 0) ? dW0 : (layer == 1) ? dW1 : (layer == 2) ? dW2 : dW3;
    const float* dB = (layer == 0) ? dB0 : (layer == 1) ? dB1 : (layer == 2) ? dB2 : dB3;
    float acc = 0.f;
#pragma unroll
    for (int r = 0; r < 32; ++r)
      acc += (0.1f * fq(dB[o * 32 + r])) * (0.1f * fq(dW[r * 16 + g]));
    __bf16* ext = wq + (size_t)((layer << 10) | o) * KEXT + 1024;
    ext[g] = (__bf16)(20.f * acc);
#pragma unroll
    for (int k = 0; k < 3; ++k) ext[16 + g * 3 + k] = (__bf16)0.f;
  }
}

// ---------------- GEMM (8-wave, counted-vmcnt dbuf + swizzle + K-ext + T1) --
// Identical to round 12.
__global__ __launch_bounds__(512) void k_gemm(
    const __bf16* __restrict__ A,       // [4096][1088]
    const __bf16* __restrict__ Wq,      // [4][1024][1088]
    __bf16* __restrict__ qout,          // [bh][n][64]
    __bf16* __restrict__ kout,          // [bh][n][64]
    __bf16* __restrict__ vout,          // [bh][64][n] (sigma-permuted n)
    float* __restrict__ fout,           // [4096][1024]
    int mode, int layer_base) {
  __shared__ __align__(16) __bf16 lA[2][128 * 64];
  __shared__ __align__(16) __bf16 lB[2][128 * 64];

  const int t = threadIdx.x;           // 0..511
  const int lane = t & 63;
  const int wv = t >> 6;               // 0..7

  int bm, bn, z;
  {
    int xcd = blockIdx.x & 7, local = blockIdx.x >> 3;
    if (mode == 0) {                     // 768 blocks: local 0..95 = 8bm x 12zn
      int bm_l = local / 12, zn_l = local - bm_l * 12;
      bm = ((xcd >> 1) << 3) + bm_l;
      int zn = (xcd & 1) * 12 + zn_l;
      z = zn >> 3;
      bn = zn & 7;
    } else {                             // 256 blocks: local 0..31 = 8bm x 4bn
      int bm_l = local >> 2, bn_l = local & 3;
      bm = ((xcd >> 1) << 3) + bm_l;
      bn = (xcd & 1) * 4 + bn_l;
      z = 0;
    }
  }
  const int layer = layer_base + z;
  const __bf16* Wl = Wq + (size_t)layer * 1024 * KEXT;
  const int wm = wv >> 2, wn = wv & 3;   // 2 x 4 wave grid
  const int fr = lane & 15, fq4 = lane >> 4;

  const int tr = t >> 3;                      // 0..63
  const int scol = ((t & 7) ^ (tr & 7)) * 8;

  f32x4 acc[4][2];
#pragma unroll
  for (int mi = 0; mi < 4; ++mi)
#pragma unroll
    for (int ni = 0; ni < 2; ++ni) { f32x4 zz = {0.f, 0.f, 0.f, 0.f}; acc[mi][ni] = zz; }

#define STAGE(kt, buf)                                                         \
  {                                                                            \
    _Pragma("unroll") for (int i = 0; i < 2; ++i) {                            \
      int row = i * 64 + tr;                                                   \
      gld16(A + (size_t)(bm * 128 + row) * KEXT + (kt)*64 + scol,              \
            (char*)lA[buf] + (i * 512 + wv * 64) * 16);                        \
      gld16(Wl + (size_t)(bn * 128 + row) * KEXT + (kt)*64 + scol,             \
            (char*)lB[buf] + (i * 512 + wv * 64) * 16);                        \
    }                                                                          \
  }
#define KCOMPUTE(CUR)                                                          \
  {                                                                            \
    _Pragma("unroll") for (int kk = 0; kk < 2; ++kk) {                         \
      bf16x8 af[4], bfr[2];                                                    \
      _Pragma("unroll") for (int mi = 0; mi < 4; ++mi)                         \
        af[mi] = *(const bf16x8*)&lA[CUR][(wm * 64 + mi * 16 + fr) * 64 +      \
                                          (((kk << 2) | fq4) ^ (fr & 7)) * 8]; \
      _Pragma("unroll") for (int ni = 0; ni < 2; ++ni)                         \
        bfr[ni] = *(const bf16x8*)&lB[CUR][(wn * 32 + ni * 16 + fr) * 64 +     \
                                           (((kk << 2) | fq4) ^ (fr & 7)) * 8];\
      _Pragma("unroll") for (int mi = 0; mi < 4; ++mi)                         \
        _Pragma("unroll") for (int ni = 0; ni < 2; ++ni)                       \
            acc[mi][ni] = MFMA(af[mi], bfr[ni], acc[mi][ni]);                  \
    }                                                                          \
  }

  STAGE(0, 0);
  int cur = 0;
  for (int kt = 0; kt < 16; ++kt) {
    STAGE(kt + 1, cur ^ 1);
    asm volatile("s_waitcnt vmcnt(4)" ::: "memory");
    __builtin_amdgcn_s_barrier();
    __builtin_amdgcn_sched_barrier(0);
    __builtin_amdgcn_s_setprio(1);
    KCOMPUTE(cur);
    __builtin_amdgcn_s_setprio(0);
    __builtin_amdgcn_sched_barrier(0);
    __builtin_amdgcn_s_barrier();
    cur ^= 1;
  }
  asm volatile("s_waitcnt vmcnt(0)" ::: "memory");
  __builtin_amdgcn_s_barrier();
  __builtin_amdgcn_sched_barrier(0);
  KCOMPUTE(cur);
  __syncthreads();
#undef STAGE
#undef KCOMPUTE

  const float outmul =
      (mode == 0 && z == 0) ? 0.1f * 0.125f * 1.4426950408889634f : 0.1f;

  if (mode == 0 && z == 2) {
    __bf16* lw = ((__bf16*)lA) + wv * 2048;   // 4KB wave-private
#pragma unroll
    for (int mi = 0; mi < 4; ++mi) {
      int cc = mi * 2 + (fq4 >> 1), qq = fq4 & 1;
      int sb = (((cc & 4) | (qq << 1) | (cc & 1)) << 3) | ((cc & 2) << 1);
      int lc = sb >> 3, half = (sb >> 2) & 1;
#pragma unroll
      for (int ni = 0; ni < 2; ++ni) {
        int dl = ni * 16 + fr;
        __bf16 pk[4];
#pragma unroll
        for (int j = 0; j < 4; ++j) pk[j] = (__bf16)(acc[mi][ni][j] * outmul);
        *(uint2*)&lw[dl * 64 + ((lc ^ (dl & 7)) << 3) + half * 4] = *(uint2*)pk;
      }
    }
    int dl = lane >> 1, c0 = (lane & 1) * 4;
    int m0 = bm * 128 + wm * 64;
    int b = m0 >> 11, n0 = m0 & 2047;
    int h = bn * 2 + (wn >> 1);
    int dg = (wn & 1) * 32 + dl;
    __bf16* vrow = vout + ((size_t)(b * 16 + h) * 64 + dg) * 2048 + n0;
#pragma unroll
    for (int lc2 = 0; lc2 < 4; ++lc2) {
      int c = c0 + lc2;
      uint4 val = *(uint4*)&lw[dl * 64 + ((c ^ (dl & 7)) << 3)];
      *(uint4*)(vrow + c * 8) = val;
    }
  } else {
#pragma unroll
    for (int mi = 0; mi < 4; ++mi)
#pragma unroll
      for (int ni = 0; ni < 2; ++ni) {
        int o = bn * 128 + wn * 32 + ni * 16 + fr;
#pragma unroll
        for (int j = 0; j < 4; ++j) {
          int m = bm * 128 + wm * 64 + mi * 16 + fq4 * 4 + j;
          float v = acc[mi][ni][j] * outmul;
          if (mode == 0) {
            int b = m >> 11, nr = m & 2047;
            int h = o >> 6, d = o & 63;
            if (z == 0)
              qout[((size_t)(b * 16 + h) * 2048 + nr) * 64 + d] = (__bf16)v;
            else
              kout[((size_t)(b * 16 + h) * 2048 + nr) * 64 + d] = (__bf16)v;
          } else {
            fout[(size_t)m * 1024 + o] = v;
          }
        }
      }
  }
}

// ---------------- flash attention partial (split-K, round-9 pipeline) -------
// Grid 1024: xcd rect = 4bh x {16qt x 2kh}. Each block: 16 K-tiles.
// kh=0 partial -> attnb (bf16, unnormalized); kh=1 -> pbuf. Denoms f32.
__global__ __launch_bounds__(256) void k_attn(
    const __bf16* __restrict__ qb,   // [bh][n][64] (pre-scaled, log2 domain)
    const __bf16* __restrict__ kb,   // [bh][n][64]
    const __bf16* __restrict__ vbt,  // [bh][64][n] (sigma-permuted n)
    __bf16* __restrict__ attnb,      // [4096][1088] (kh=0 partial o)
    __bf16* __restrict__ pbuf,       // [32][2048][64] (kh=1 partial o)
    float* __restrict__ dbuf) {      // [2][32][2048] denominators
  __shared__ __align__(16) __bf16 lK[2][64 * 64];
  __shared__ __align__(16) __bf16 lVT[2][64 * 64];

  const int t = threadIdx.x, lane = t & 63, wv = t >> 6;
  const int xcd = blockIdx.x & 7, local = blockIdx.x >> 3;   // local 0..127
  const int bh = xcd * 4 + (local >> 5);
  const int r5 = local & 31;
  const int qt = r5 >> 1;                      // 0..15
  const int kh = r5 & 1;                       // key half
  const int kb0 = kh * 16;
  const int fr = lane & 15, g = lane >> 4;
  const int qrow0 = qt * 128 + wv * 16;
  const size_t hbase = (size_t)bh * 2048 * 64;

  const int srow0 = t >> 3, sc0 = (t & 7) ^ (srow0 & 7);
  const int srow1 = (256 + t) >> 3, sc1 = (t & 7) ^ (srow1 & 7);
  const int dst0 = (wv * 64) * 16, dst1 = (256 + wv * 64) * 16;

  bf16x8 qf[2][2];
#pragma unroll
  for (int s = 0; s < 2; ++s)
#pragma unroll
    for (int kk = 0; kk < 2; ++kk)
      qf[s][kk] = *(const bf16x8*)(qb + hbase + (size_t)(qrow0 + s * 64 + fr) * 64 +
                                   kk * 32 + g * 8);

  bf16x8 vones;
#pragma unroll
  for (int e = 0; e < 8; ++e) vones[e] = (__bf16)1.0f;

  f32x4 o[2][4], o4[2];
#pragma unroll
  for (int s = 0; s < 2; ++s) {
#pragma unroll
    for (int di = 0; di < 4; ++di) { f32x4 zz = {0.f, 0.f, 0.f, 0.f}; o[s][di] = zz; }
    f32x4 zz = {0.f, 0.f, 0.f, 0.f};
    o4[s] = zz;
  }

  f32x4 smA[2][4], smB[2][4];

#define SK_STAGE(KT, BUF)                                                      \
  {                                                                            \
    int kn = (KT)*64;                                                          \
    gld16(kb + hbase + (size_t)(kn + srow0) * 64 + sc0 * 8, (char*)(BUF) + dst0); \
    gld16(kb + hbase + (size_t)(kn + srow1) * 64 + sc1 * 8, (char*)(BUF) + dst1); \
  }
#define SV_STAGE(KT, BUF)                                                      \
  {                                                                            \
    int kn = (KT)*64;                                                          \
    gld16(vbt + hbase + (size_t)srow0 * 2048 + kn + sc0 * 8, (char*)(BUF) + dst0); \
    gld16(vbt + hbase + (size_t)srow1 * 2048 + kn + sc1 * 8, (char*)(BUF) + dst1); \
  }
#define QK_STEP(KBUF, SM)                                                      \
  {                                                                            \
    _Pragma("unroll") for (int ni = 0; ni < 4; ++ni) {                         \
      f32x4 zz = {0.f, 0.f, 0.f, 0.f};                                         \
      SM[0][ni] = zz;                                                          \
      SM[1][ni] = zz;                                                          \
    }                                                                          \
    _Pragma("unroll") for (int kk = 0; kk < 2; ++kk)                           \
        _Pragma("unroll") for (int ni = 0; ni < 4; ++ni) {                     \
      bf16x8 kf = *(const bf16x8*)&(KBUF)[(ni * 16 + fr) * 64 +                \
                                          (((kk << 2) | g) ^ (fr & 7)) * 8];   \
      SM[0][ni] = MFMA(kf, qf[0][kk], SM[0][ni]);                              \
      SM[1][ni] = MFMA(kf, qf[1][kk], SM[1][ni]);                              \
    }                                                                          \
  }
#define EXPPV_STEP(SM, VBUF)                                                   \
  {                                                                            \
    bf16x8 pa[2][2];                                                           \
    _Pragma("unroll") for (int s2 = 0; s2 < 2; ++s2)                           \
        _Pragma("unroll") for (int kk = 0; kk < 2; ++kk)                       \
            _Pragma("unroll") for (int e = 0; e < 8; ++e)                      \
                pa[s2][kk][e] = (__bf16)__builtin_amdgcn_exp2f(                \
                    SM[s2][2 * kk + (e >> 2)][e & 3]);                         \
    _Pragma("unroll") for (int kk = 0; kk < 2; ++kk) {                         \
      const int ncr = ((kk << 2) | ((g & 1) << 1) | (g >> 1)) ^ (fr & 7);      \
      _Pragma("unroll") for (int di = 0; di < 4; ++di) {                       \
        bf16x8 vf = *(const bf16x8*)&(VBUF)[(di * 16 + fr) * 64 + ncr * 8];    \
        o[0][di] = MFMA(pa[0][kk], vf, o[0][di]);                              \
        o[1][di] = MFMA(pa[1][kk], vf, o[1][di]);                              \
      }                                                                        \
      o4[0] = MFMA(pa[0][kk], vones, o4[0]);                                   \
      o4[1] = MFMA(pa[1][kk], vones, o4[1]);                                   \
    }                                                                          \
  }
#define WAITBAR(N)                                                             \
  asm volatile("s_waitcnt vmcnt(" #N ")" ::: "memory");                        \
  __builtin_amdgcn_s_barrier();                                                \
  __builtin_amdgcn_sched_barrier(0);
#define ENDBAR                                                                 \
  __builtin_amdgcn_sched_barrier(0);                                           \
  __builtin_amdgcn_s_barrier();

  // prologue: K(kb0) staged
  SK_STAGE(kb0, lK[0]);

  for (int it = 0; it < 7; ++it) {
    int t2 = kb0 + it * 2;
    // ---- even half ----
    SK_STAGE(t2 + 1, lK[1]);
    SV_STAGE(t2, lVT[0]);
    WAITBAR(4)
    __builtin_amdgcn_s_setprio(1);
    QK_STEP(lK[0], smB);
    if (it > 0) { EXPPV_STEP(smA, lVT[1]); }
    __builtin_amdgcn_s_setprio(0);
    ENDBAR
    // ---- odd half ----
    SK_STAGE(t2 + 2, lK[0]);
    SV_STAGE(t2 + 1, lVT[1]);
    WAITBAR(4)
    __builtin_amdgcn_s_setprio(1);
    QK_STEP(lK[1], smA);
    EXPPV_STEP(smB, lVT[0]);
    __builtin_amdgcn_s_setprio(0);
    ENDBAR
  }
  // ---- peeled: tiles kb0+14, kb0+15 ----
  SK_STAGE(kb0 + 15, lK[1]);
  SV_STAGE(kb0 + 14, lVT[0]);
  WAITBAR(4)
  __builtin_amdgcn_s_setprio(1);
  QK_STEP(lK[0], smB);
  EXPPV_STEP(smA, lVT[1]);
  __builtin_amdgcn_s_setprio(0);
  ENDBAR
  SV_STAGE(kb0 + 15, lVT[1]);
  WAITBAR(2)
  __builtin_amdgcn_s_setprio(1);
  QK_STEP(lK[1], smA);
  EXPPV_STEP(smB, lVT[0]);
  __builtin_amdgcn_s_setprio(0);
  ENDBAR
  WAITBAR(0)
  EXPPV_STEP(smA, lVT[1]);

#undef SK_STAGE
#undef SV_STAGE
#undef QK_STEP
#undef EXPPV_STEP
#undef WAITBAR
#undef ENDBAR

  // epilogue: write UNNORMALIZED bf16 partials + f32 denominators
  const int b = bh >> 4, h = bh & 15;
#pragma unroll
  for (int s = 0; s < 2; ++s)
#pragma unroll
    for (int j = 0; j < 4; ++j) {
      int rl = qt * 128 + s * 64 + wv * 16 + g * 4 + j;   // 0..2047 within bh
      if (kh == 0) {
        size_t rowbase = (size_t)(b * 2048 + rl) * KEXT + h * 64;
#pragma unroll
        for (int di = 0; di < 4; ++di)
          attnb[rowbase + di * 16 + fr] = (__bf16)o[s][di][j];
        if (fr == 0) dbuf[bh * 2048 + rl] = o4[s][j];
      } else {
        size_t pbase = ((size_t)bh * 2048 + rl) * 64;
#pragma unroll
        for (int di = 0; di < 4; ++di)
          pbuf[pbase + di * 16 + fr] = (__bf16)o[s][di][j];
        if (fr == 0) dbuf[65536 + bh * 2048 + rl] = o4[s][j];
      }
    }
}

// ---------------- merge: out = (o0+o1)/(l0+l1), + head means + pad ----------
__global__ __launch_bounds__(256) void k_merge(
    __bf16* __restrict__ attnb,      // [4096][1088] in: kh0 partial; out: final
    const __bf16* __restrict__ pbuf, // [32][2048][64] kh1 partial
    const float* __restrict__ dbuf) {// [2][32][2048]
  int row = blockIdx.x;              // 0..4095 = b*2048+nr
  int t = threadIdx.x;
  int b = row >> 11, nr = row & 2047;
  int h = t >> 4, d0 = (t & 15) * 4;
  int bh = b * 16 + h;

  float l = dbuf[bh * 2048 + nr] + dbuf[65536 + bh * 2048 + nr];
  float inv = 1.f / l;

  __bf16* ap = attnb + (size_t)row * KEXT + h * 64 + d0;
  const __bf16* pp = pbuf + ((size_t)bh * 2048 + nr) * 64 + d0;
  uint2 a2 = *(const uint2*)ap;
  uint2 p2 = *(const uint2*)pp;
  const __bf16* av = (const __bf16*)&a2;
  const __bf16* pv = (const __bf16*)&p2;
  __bf16 outv[4];
  float rowsum = 0.f;
#pragma unroll
  for (int j = 0; j < 4; ++j) {
    float vv = ((float)av[j] + (float)pv[j]) * inv;
    outv[j] = (__bf16)vv;
    rowsum += vv;
  }
  *(uint2*)ap = *(uint2*)outv;
  rowsum = redsum16(rowsum);         // sum over the head's 64 d-values
  __bf16* ext = attnb + (size_t)row * KEXT + 1024;
  if ((t & 15) == 0) ext[h] = (__bf16)(rowsum * (1.f / 64.f));
  if (t < 48) ext[16 + t] = (__bf16)0.f;
}

// ---------------- launch ----------------
extern "C" void kernel_launch(void* const* d_in, const int* in_sizes, int n_in,
                              void* d_out, int out_size, void* d_ws, size_t ws_size,
                              hipStream_t stream) {
  const float* x = (const float*)d_in[0];
  float* out = (float*)d_out;

  char* ws = (char*)d_ws;
  const size_t MB = 1ull << 20;
  __bf16* xbf   = (__bf16*)(ws);                 // 4096*1088*2 = 8.9 MB
  __bf16* attnb = xbf;                           // alias: xbf dead after QKV GEMM
  __bf16* wq    = (__bf16*)(ws + 9 * MB);        // 4*1024*1088*2 = 8.9 MB
  __bf16* qb    = (__bf16*)(ws + 18 * MB);       // 8 MB
  __bf16* kb    = (__bf16*)(ws + 26 * MB);       // 8 MB
  __bf16* vbt   = (__bf16*)(ws + 34 * MB);       // 8 MB
  __bf16* pbuf  = (__bf16*)(ws + 42 * MB);       // 32*2048*64*2 = 8 MB
  float*  dbuf  = (float*)(ws + 50 * MB);        // 2*32*2048*4 = 512 KB -> 50.5 MB

  k_prep<<<8448, 256, 0, stream>>>(
      x, (const float*)d_in[1], (const float*)d_in[4], (const float*)d_in[7],
      (const float*)d_in[10], (const float*)d_in[2], (const float*)d_in[3],
      (const float*)d_in[5], (const float*)d_in[6], (const float*)d_in[8],
      (const float*)d_in[9], (const float*)d_in[11], (const float*)d_in[12],
      wq, xbf);
  k_gemm<<<768, 512, 0, stream>>>(xbf, wq, qb, kb, vbt, nullptr, 0, 0);
  k_attn<<<1024, 256, 0, stream>>>(qb, kb, vbt, attnb, pbuf, dbuf);
  k_merge<<<4096, 256, 0, stream>>>(attnb, pbuf, dbuf);
  k_gemm<<<256, 512, 0, stream>>>(attnb, wq, nullptr, nullptr, nullptr,
                                  out, 1, 3);
}

// Round 14
// 112.544 us; speedup vs baseline: 1.0647x; 1.0647x over previous
//
#include <hip/hip_runtime.h>

// ---------------------------------------------------------------------------
// SelfAttention with QA-LoRA quantized projections, MI355X (gfx950)
// Round 14: round-12 base (best, 113.1us) + attn single-barrier 4-deep K/V
//           rotation: per tile issue SK(t+2)/SV(t+1), vmcnt(8), ONE barrier,
//           QK(t)||expPV(t-1). Barriers 64->33/block. Split-K and fused
//           prep (round 13) reverted. GEMMs identical to round 12.
// ---------------------------------------------------------------------------

typedef __bf16 bf16x8 __attribute__((ext_vector_type(8)));
typedef float f32x4 __attribute__((ext_vector_type(4)));

#define MFMA(a, b, c) __builtin_amdgcn_mfma_f32_16x16x32_bf16(a, b, c, 0, 0, 0)

#define KEXT 1088   // 1024 + 64 extension cols (16 LoRA + 48 zeros)

__device__ __forceinline__ void gld16(const void* g, void* l) {
  __builtin_amdgcn_global_load_lds(
      (const __attribute__((address_space(1))) void*)g,
      (__attribute__((address_space(3))) void*)l, 16, 0, 0);
}

// fake_quantize: returns the clipped, round-half-even INTEGER (not dequantized).
__device__ __forceinline__ float fq(float v) {
  float q = rintf(v / 0.1f);           // v_rndne_f32: round half to even
  return fminf(fmaxf(q, -128.f), 127.f);
}

__device__ __forceinline__ float redsum16(float v) {
  v += __shfl_xor(v, 1);
  v += __shfl_xor(v, 2);
  v += __shfl_xor(v, 4);
  v += __shfl_xor(v, 8);
  return v;
}

// ---------------- prep kernels ----------------

// weights -> bf16 int codes into stride-1088 layout
__global__ __launch_bounds__(256) void k_quant_w(
    const float* __restrict__ w0, const float* __restrict__ w1,
    const float* __restrict__ w2, const float* __restrict__ w3,
    __bf16* __restrict__ wq) {
  int i = blockIdx.x * 256 + threadIdx.x;          // 4 * 1024 * 256
  int layer = i >> 18, rest = i & 262143;
  int o = rest >> 8, c4 = rest & 255;
  const float* src = (layer == 0) ? w0 : (layer == 1) ? w1 : (layer == 2) ? w2 : w3;
  float4 v = ((const float4*)src)[rest];
  __bf16 r[4] = {(__bf16)fq(v.x), (__bf16)fq(v.y), (__bf16)fq(v.z), (__bf16)fq(v.w)};
  *(uint2*)(wq + (size_t)((layer << 10) | o) * KEXT + (c4 << 2)) = *(uint2*)r;
}

// fused: x fp32 -> bf16 (stride 1088) AND extension cols = group means.
__global__ __launch_bounds__(256) void k_xprep(const float* __restrict__ x,
                                               __bf16* __restrict__ xbf) {
  int row = blockIdx.x, t = threadIdx.x;
  float4 v = ((const float4*)(x + (size_t)row * 1024))[t];
  __bf16 r[4] = {(__bf16)v.x, (__bf16)v.y, (__bf16)v.z, (__bf16)v.w};
  *(uint2*)(xbf + (size_t)row * KEXT + 4 * t) = *(uint2*)r;
  float s = v.x + v.y + v.z + v.w;
  s = redsum16(s);                                  // all 16 lanes of group hold sum
  int g = t >> 4, j = t & 15;
  __bf16* ext = xbf + (size_t)row * KEXT + 1024;
  if (j == 0) ext[g] = (__bf16)(s * (1.f / 64.f));
  else if (j < 4) ext[16 + g * 3 + (j - 1)] = (__bf16)0.f;   // zero cols 1040..1087
}

// LoRA delta -> extension cols of wq: wq_ext[o][g] = bf16(20 * dBq@dWq * 0.01)
__global__ __launch_bounds__(256) void k_delta(
    const float* __restrict__ dW0, const float* __restrict__ dB0,
    const float* __restrict__ dW1, const float* __restrict__ dB1,
    const float* __restrict__ dW2, const float* __restrict__ dB2,
    const float* __restrict__ dW3, const float* __restrict__ dB3,
    __bf16* __restrict__ wq) {
  int i = blockIdx.x * 256 + threadIdx.x;          // 65536 = 4*1024*16
  int layer = i >> 14, o = (i >> 4) & 1023, g = i & 15;
  const float* dW = (layer == 0) ? dW0 : (layer == 1) ? dW1 : (layer == 2) ? dW2 : dW3;
  const float* dB = (layer == 0) ? dB0 : (layer == 1) ? dB1 : (layer == 2) ? dB2 : dB3;
  float acc = 0.f;
#pragma unroll
  for (int r = 0; r < 32; ++r)
    acc += (0.1f * fq(dB[o * 32 + r])) * (0.1f * fq(dW[r * 16 + g]));
  __bf16* ext = wq + (size_t)((layer << 10) | o) * KEXT + 1024;
  ext[g] = (__bf16)(20.f * acc);
#pragma unroll
  for (int k = 0; k < 3; ++k) ext[16 + g * 3 + k] = (__bf16)0.f;
}

// ---------------- GEMM (8-wave, counted-vmcnt dbuf + swizzle + K-ext + T1) --
// Identical to round 12.
__global__ __launch_bounds__(512) void k_gemm(
    const __bf16* __restrict__ A,       // [4096][1088]
    const __bf16* __restrict__ Wq,      // [4][1024][1088]
    __bf16* __restrict__ qout,          // [bh][n][64]
    __bf16* __restrict__ kout,          // [bh][n][64]
    __bf16* __restrict__ vout,          // [bh][64][n] (sigma-permuted n)
    float* __restrict__ fout,           // [4096][1024]
    int mode, int layer_base) {
  __shared__ __align__(16) __bf16 lA[2][128 * 64];
  __shared__ __align__(16) __bf16 lB[2][128 * 64];

  const int t = threadIdx.x;           // 0..511
  const int lane = t & 63;
  const int wv = t >> 6;               // 0..7

  int bm, bn, z;
  {
    int xcd = blockIdx.x & 7, local = blockIdx.x >> 3;
    if (mode == 0) {                     // 768 blocks: local 0..95 = 8bm x 12zn
      int bm_l = local / 12, zn_l = local - bm_l * 12;
      bm = ((xcd >> 1) << 3) + bm_l;
      int zn = (xcd & 1) * 12 + zn_l;
      z = zn >> 3;
      bn = zn & 7;
    } else {                             // 256 blocks: local 0..31 = 8bm x 4bn
      int bm_l = local >> 2, bn_l = local & 3;
      bm = ((xcd >> 1) << 3) + bm_l;
      bn = (xcd & 1) * 4 + bn_l;
      z = 0;
    }
  }
  const int layer = layer_base + z;
  const __bf16* Wl = Wq + (size_t)layer * 1024 * KEXT;
  const int wm = wv >> 2, wn = wv & 3;   // 2 x 4 wave grid
  const int fr = lane & 15, fq4 = lane >> 4;

  const int tr = t >> 3;                      // 0..63
  const int scol = ((t & 7) ^ (tr & 7)) * 8;

  f32x4 acc[4][2];
#pragma unroll
  for (int mi = 0; mi < 4; ++mi)
#pragma unroll
    for (int ni = 0; ni < 2; ++ni) { f32x4 zz = {0.f, 0.f, 0.f, 0.f}; acc[mi][ni] = zz; }

#define STAGE(kt, buf)                                                         \
  {                                                                            \
    _Pragma("unroll") for (int i = 0; i < 2; ++i) {                            \
      int row = i * 64 + tr;                                                   \
      gld16(A + (size_t)(bm * 128 + row) * KEXT + (kt)*64 + scol,              \
            (char*)lA[buf] + (i * 512 + wv * 64) * 16);                        \
      gld16(Wl + (size_t)(bn * 128 + row) * KEXT + (kt)*64 + scol,             \
            (char*)lB[buf] + (i * 512 + wv * 64) * 16);                        \
    }                                                                          \
  }
#define KCOMPUTE(CUR)                                                          \
  {                                                                            \
    _Pragma("unroll") for (int kk = 0; kk < 2; ++kk) {                         \
      bf16x8 af[4], bfr[2];                                                    \
      _Pragma("unroll") for (int mi = 0; mi < 4; ++mi)                         \
        af[mi] = *(const bf16x8*)&lA[CUR][(wm * 64 + mi * 16 + fr) * 64 +      \
                                          (((kk << 2) | fq4) ^ (fr & 7)) * 8]; \
      _Pragma("unroll") for (int ni = 0; ni < 2; ++ni)                         \
        bfr[ni] = *(const bf16x8*)&lB[CUR][(wn * 32 + ni * 16 + fr) * 64 +     \
                                           (((kk << 2) | fq4) ^ (fr & 7)) * 8];\
      _Pragma("unroll") for (int mi = 0; mi < 4; ++mi)                         \
        _Pragma("unroll") for (int ni = 0; ni < 2; ++ni)                       \
            acc[mi][ni] = MFMA(af[mi], bfr[ni], acc[mi][ni]);                  \
    }                                                                          \
  }

  STAGE(0, 0);
  int cur = 0;
  for (int kt = 0; kt < 16; ++kt) {
    STAGE(kt + 1, cur ^ 1);
    asm volatile("s_waitcnt vmcnt(4)" ::: "memory");
    __builtin_amdgcn_s_barrier();
    __builtin_amdgcn_sched_barrier(0);
    __builtin_amdgcn_s_setprio(1);
    KCOMPUTE(cur);
    __builtin_amdgcn_s_setprio(0);
    __builtin_amdgcn_sched_barrier(0);
    __builtin_amdgcn_s_barrier();
    cur ^= 1;
  }
  asm volatile("s_waitcnt vmcnt(0)" ::: "memory");
  __builtin_amdgcn_s_barrier();
  __builtin_amdgcn_sched_barrier(0);
  KCOMPUTE(cur);
  __syncthreads();
#undef STAGE
#undef KCOMPUTE

  const float outmul =
      (mode == 0 && z == 0) ? 0.1f * 0.125f * 1.4426950408889634f : 0.1f;

  if (mode == 0 && z == 2) {
    __bf16* lw = ((__bf16*)lA) + wv * 2048;   // 4KB wave-private
#pragma unroll
    for (int mi = 0; mi < 4; ++mi) {
      int cc = mi * 2 + (fq4 >> 1), qq = fq4 & 1;
      int sb = (((cc & 4) | (qq << 1) | (cc & 1)) << 3) | ((cc & 2) << 1);
      int lc = sb >> 3, half = (sb >> 2) & 1;
#pragma unroll
      for (int ni = 0; ni < 2; ++ni) {
        int dl = ni * 16 + fr;
        __bf16 pk[4];
#pragma unroll
        for (int j = 0; j < 4; ++j) pk[j] = (__bf16)(acc[mi][ni][j] * outmul);
        *(uint2*)&lw[dl * 64 + ((lc ^ (dl & 7)) << 3) + half * 4] = *(uint2*)pk;
      }
    }
    int dl = lane >> 1, c0 = (lane & 1) * 4;
    int m0 = bm * 128 + wm * 64;
    int b = m0 >> 11, n0 = m0 & 2047;
    int h = bn * 2 + (wn >> 1);
    int dg = (wn & 1) * 32 + dl;
    __bf16* vrow = vout + ((size_t)(b * 16 + h) * 64 + dg) * 2048 + n0;
#pragma unroll
    for (int lc2 = 0; lc2 < 4; ++lc2) {
      int c = c0 + lc2;
      uint4 val = *(uint4*)&lw[dl * 64 + ((c ^ (dl & 7)) << 3)];
      *(uint4*)(vrow + c * 8) = val;
    }
  } else {
#pragma unroll
    for (int mi = 0; mi < 4; ++mi)
#pragma unroll
      for (int ni = 0; ni < 2; ++ni) {
        int o = bn * 128 + wn * 32 + ni * 16 + fr;
#pragma unroll
        for (int j = 0; j < 4; ++j) {
          int m = bm * 128 + wm * 64 + mi * 16 + fq4 * 4 + j;
          float v = acc[mi][ni][j] * outmul;
          if (mode == 0) {
            int b = m >> 11, nr = m & 2047;
            int h = o >> 6, d = o & 63;
            if (z == 0)
              qout[((size_t)(b * 16 + h) * 2048 + nr) * 64 + d] = (__bf16)v;
            else
              kout[((size_t)(b * 16 + h) * 2048 + nr) * 64 + d] = (__bf16)v;
          } else {
            fout[(size_t)m * 1024 + o] = v;
          }
        }
      }
  }
}

// ---------------- flash attention (round 14: 4-deep, ONE barrier/tile) ------
// Per tile t: issue SK(t+2)->lK[(t+2)&3], SV(t+1)->lVT[(t+1)&3]; vmcnt(8)
// (keeps tiles t,t-1 in flight); one barrier; QK(t) || expPV(t-1).
// WAR safe: writer of buf b at tile t passed barrier(t-1); last reader of b
// (tile t-2 compute) precedes barrier(t-1) in every wave's program order.
__global__ __launch_bounds__(256) void k_attn(
    const __bf16* __restrict__ qb,   // [bh][n][64] (pre-scaled, log2 domain)
    const __bf16* __restrict__ kb,   // [bh][n][64]
    const __bf16* __restrict__ vbt,  // [bh][64][n] (sigma-permuted n)
    __bf16* __restrict__ attnb) {    // [4096][1088] (ext cols = head means)
  __shared__ __align__(16) __bf16 lK[4][64 * 64];
  __shared__ __align__(16) __bf16 lVT[4][64 * 64];

  const int t = threadIdx.x, lane = t & 63, wv = t >> 6;
  // T1: XCD rect = 4bh x 16qt -> each bh's K/V fetched by one XCD only
  const int xcd = blockIdx.x & 7, local = blockIdx.x >> 3;   // local 0..63
  const int bh = xcd * 4 + (local >> 4);
  const int qt = local & 15;                   // 0..15 (128 q-rows per block)
  const int fr = lane & 15, g = lane >> 4;
  const int qrow0 = qt * 128 + wv * 16;
  const size_t hbase = (size_t)bh * 2048 * 64;

  const int srow0 = t >> 3, sc0 = (t & 7) ^ (srow0 & 7);
  const int srow1 = (256 + t) >> 3, sc1 = (t & 7) ^ (srow1 & 7);
  const int dst0 = (wv * 64) * 16, dst1 = (256 + wv * 64) * 16;

  bf16x8 qf[2][2];
#pragma unroll
  for (int s = 0; s < 2; ++s)
#pragma unroll
    for (int kk = 0; kk < 2; ++kk)
      qf[s][kk] = *(const bf16x8*)(qb + hbase + (size_t)(qrow0 + s * 64 + fr) * 64 +
                                   kk * 32 + g * 8);

  bf16x8 vones;
#pragma unroll
  for (int e = 0; e < 8; ++e) vones[e] = (__bf16)1.0f;

  f32x4 o[2][4], o4[2];
#pragma unroll
  for (int s = 0; s < 2; ++s) {
#pragma unroll
    for (int di = 0; di < 4; ++di) { f32x4 zz = {0.f, 0.f, 0.f, 0.f}; o[s][di] = zz; }
    f32x4 zz = {0.f, 0.f, 0.f, 0.f};
    o4[s] = zz;
  }

  f32x4 smA[2][4], smB[2][4];

#define SK_STAGE(KT, BUF)                                                      \
  {                                                                            \
    int kn = (KT)*64;                                                          \
    gld16(kb + hbase + (size_t)(kn + srow0) * 64 + sc0 * 8, (char*)(BUF) + dst0); \
    gld16(kb + hbase + (size_t)(kn + srow1) * 64 + sc1 * 8, (char*)(BUF) + dst1); \
  }
#define SV_STAGE(KT, BUF)                                                      \
  {                                                                            \
    int kn = (KT)*64;                                                          \
    gld16(vbt + hbase + (size_t)srow0 * 2048 + kn + sc0 * 8, (char*)(BUF) + dst0); \
    gld16(vbt + hbase + (size_t)srow1 * 2048 + kn + sc1 * 8, (char*)(BUF) + dst1); \
  }
#define QK_STEP(KBUF, SM)                                                      \
  {                                                                            \
    _Pragma("unroll") for (int ni = 0; ni < 4; ++ni) {                         \
      f32x4 zz = {0.f, 0.f, 0.f, 0.f};                                         \
      SM[0][ni] = zz;                                                          \
      SM[1][ni] = zz;                                                          \
    }                                                                          \
    _Pragma("unroll") for (int kk = 0; kk < 2; ++kk)                           \
        _Pragma("unroll") for (int ni = 0; ni < 4; ++ni) {                     \
      bf16x8 kf = *(const bf16x8*)&(KBUF)[(ni * 16 + fr) * 64 +                \
                                          (((kk << 2) | g) ^ (fr & 7)) * 8];   \
      SM[0][ni] = MFMA(kf, qf[0][kk], SM[0][ni]);                              \
      SM[1][ni] = MFMA(kf, qf[1][kk], SM[1][ni]);                              \
    }                                                                          \
  }
#define EXPPV_STEP(SM, VBUF)                                                   \
  {                                                                            \
    bf16x8 pa[2][2];                                                           \
    _Pragma("unroll") for (int s2 = 0; s2 < 2; ++s2)                           \
        _Pragma("unroll") for (int kk = 0; kk < 2; ++kk)                       \
            _Pragma("unroll") for (int e = 0; e < 8; ++e)                      \
                pa[s2][kk][e] = (__bf16)__builtin_amdgcn_exp2f(                \
                    SM[s2][2 * kk + (e >> 2)][e & 3]);                         \
    _Pragma("unroll") for (int kk = 0; kk < 2; ++kk) {                         \
      const int ncr = ((kk << 2) | ((g & 1) << 1) | (g >> 1)) ^ (fr & 7);      \
      _Pragma("unroll") for (int di = 0; di < 4; ++di) {                       \
        bf16x8 vf = *(const bf16x8*)&(VBUF)[(di * 16 + fr) * 64 + ncr * 8];    \
        o[0][di] = MFMA(pa[0][kk], vf, o[0][di]);                              \
        o[1][di] = MFMA(pa[1][kk], vf, o[1][di]);                              \
      }                                                                        \
      o4[0] = MFMA(pa[0][kk], vones, o4[0]);                                   \
      o4[1] = MFMA(pa[1][kk], vones, o4[1]);                                   \
    }                                                                          \
  }
#define WAITBAR(N)                                                             \
  asm volatile("s_waitcnt vmcnt(" #N ")" ::: "memory");                        \
  __builtin_amdgcn_s_barrier();                                                \
  __builtin_amdgcn_sched_barrier(0);

  // prologue: K(0)->lK[0], K(1)->lK[1], V(0)->lVT[0]   (6 loads in flight)
  SK_STAGE(0, lK[0]);
  SK_STAGE(1, lK[1]);
  SV_STAGE(0, lVT[0]);

  // --- tile 0 (special: no EXPPV) ---
  SK_STAGE(2, lK[2]);
  SV_STAGE(1, lVT[1]);
  WAITBAR(8)                         // prologue K(0) complete
  __builtin_amdgcn_s_setprio(1);
  QK_STEP(lK[0], smB);
  __builtin_amdgcn_s_setprio(0);

  // --- tiles 1..3 ---
  SK_STAGE(3, lK[3]);
  SV_STAGE(2, lVT[2]);
  WAITBAR(8)
  __builtin_amdgcn_s_setprio(1);
  QK_STEP(lK[1], smA);
  EXPPV_STEP(smB, lVT[0]);
  __builtin_amdgcn_s_setprio(0);

  SK_STAGE(4, lK[0]);
  SV_STAGE(3, lVT[3]);
  WAITBAR(8)
  __builtin_amdgcn_s_setprio(1);
  QK_STEP(lK[2], smB);
  EXPPV_STEP(smA, lVT[1]);
  __builtin_amdgcn_s_setprio(0);

  SK_STAGE(5, lK[1]);
  SV_STAGE(4, lVT[0]);
  WAITBAR(8)
  __builtin_amdgcn_s_setprio(1);
  QK_STEP(lK[3], smA);
  EXPPV_STEP(smB, lVT[2]);
  __builtin_amdgcn_s_setprio(0);

  // --- tiles 4..27: six 4-tile groups, fixed buffer pattern ---
  for (int gidx = 0; gidx < 6; ++gidx) {
    int t0 = 4 + gidx * 4;
    // p=0 (t0): t0&3==0
    SK_STAGE(t0 + 2, lK[2]);
    SV_STAGE(t0 + 1, lVT[1]);
    WAITBAR(8)
    __builtin_amdgcn_s_setprio(1);
    QK_STEP(lK[0], smB);
    EXPPV_STEP(smA, lVT[3]);
    __builtin_amdgcn_s_setprio(0);
    // p=1
    SK_STAGE(t0 + 3, lK[3]);
    SV_STAGE(t0 + 2, lVT[2]);
    WAITBAR(8)
    __builtin_amdgcn_s_setprio(1);
    QK_STEP(lK[1], smA);
    EXPPV_STEP(smB, lVT[0]);
    __builtin_amdgcn_s_setprio(0);
    // p=2
    SK_STAGE(t0 + 4, lK[0]);
    SV_STAGE(t0 + 3, lVT[3]);
    WAITBAR(8)
    __builtin_amdgcn_s_setprio(1);
    QK_STEP(lK[2], smB);
    EXPPV_STEP(smA, lVT[1]);
    __builtin_amdgcn_s_setprio(0);
    // p=3
    SK_STAGE(t0 + 5, lK[1]);
    SV_STAGE(t0 + 4, lVT[0]);
    WAITBAR(8)
    __builtin_amdgcn_s_setprio(1);
    QK_STEP(lK[3], smA);
    EXPPV_STEP(smB, lVT[2]);
    __builtin_amdgcn_s_setprio(0);
  }

  // --- peeled tail: tiles 28..31 ---
  // t=28
  SK_STAGE(30, lK[2]);
  SV_STAGE(29, lVT[1]);
  WAITBAR(8)
  __builtin_amdgcn_s_setprio(1);
  QK_STEP(lK[0], smB);
  EXPPV_STEP(smA, lVT[3]);
  __builtin_amdgcn_s_setprio(0);
  // t=29
  SK_STAGE(31, lK[3]);
  SV_STAGE(30, lVT[2]);
  WAITBAR(8)
  __builtin_amdgcn_s_setprio(1);
  QK_STEP(lK[1], smA);
  EXPPV_STEP(smB, lVT[0]);
  __builtin_amdgcn_s_setprio(0);
  // t=30 (no SK; outstanding after issue: t29's 4 + this 2 = 6)
  SV_STAGE(31, lVT[3]);
  WAITBAR(6)
  __builtin_amdgcn_s_setprio(1);
  QK_STEP(lK[2], smB);
  EXPPV_STEP(smA, lVT[1]);
  __builtin_amdgcn_s_setprio(0);
  // t=31 (no issues; need t29's K(31),V(30) -> leave t30's 2)
  WAITBAR(2)
  __builtin_amdgcn_s_setprio(1);
  QK_STEP(lK[3], smA);
  EXPPV_STEP(smB, lVT[2]);
  __builtin_amdgcn_s_setprio(0);
  // final: V(31)
  WAITBAR(0)
  EXPPV_STEP(smA, lVT[3]);

#undef SK_STAGE
#undef SV_STAGE
#undef QK_STEP
#undef EXPPV_STEP
#undef WAITBAR

  // epilogue: normalize, write attn bf16 into stride-1088 rows + ext cols
  const int b = bh >> 4, h = bh & 15;
#pragma unroll
  for (int s = 0; s < 2; ++s)
#pragma unroll
    for (int j = 0; j < 4; ++j) {
      float inv = 1.f / o4[s][j];
      int nr = qt * 128 + s * 64 + wv * 16 + g * 4 + j;
      size_t rowbase = (size_t)(b * 2048 + nr) * KEXT;
      float rowsum = 0.f;
#pragma unroll
      for (int di = 0; di < 4; ++di) {
        float vv = o[s][di][j] * inv;
        attnb[rowbase + h * 64 + di * 16 + fr] = (__bf16)vv;
        rowsum += vv;
      }
      rowsum = redsum16(rowsum);
      if (fr == 0) attnb[rowbase + 1024 + h] = (__bf16)(rowsum * (1.f / 64.f));
      if (h < 3) attnb[rowbase + 1040 + h * 16 + fr] = (__bf16)0.f;  // zero pad
    }
}

// ---------------- launch ----------------
extern "C" void kernel_launch(void* const* d_in, const int* in_sizes, int n_in,
                              void* d_out, int out_size, void* d_ws, size_t ws_size,
                              hipStream_t stream) {
  const float* x = (const float*)d_in[0];
  const float* w_[4]  = {(const float*)d_in[1], (const float*)d_in[4],
                         (const float*)d_in[7], (const float*)d_in[10]};
  const float* dW_[4] = {(const float*)d_in[2], (const float*)d_in[5],
                         (const float*)d_in[8], (const float*)d_in[11]};
  const float* dB_[4] = {(const float*)d_in[3], (const float*)d_in[6],
                         (const float*)d_in[9], (const float*)d_in[12]};
  float* out = (float*)d_out;

  char* ws = (char*)d_ws;
  const size_t MB = 1ull << 20;
  __bf16* xbf   = (__bf16*)(ws);                 // 4096*1088*2 = 8.9 MB
  __bf16* attnb = xbf;                           // alias: xbf dead after QKV GEMM
  __bf16* wq    = (__bf16*)(ws + 9 * MB);        // 4*1024*1088*2 = 8.9 MB
  __bf16* qb    = (__bf16*)(ws + 18 * MB);       // 8 MB
  __bf16* kb    = (__bf16*)(ws + 26 * MB);       // 8 MB
  __bf16* vbt   = (__bf16*)(ws + 34 * MB);       // 8 MB -> ends 42 MB

  k_quant_w<<<4096, 256, 0, stream>>>(w_[0], w_[1], w_[2], w_[3], wq);
  k_xprep<<<4096, 256, 0, stream>>>(x, xbf);
  k_delta<<<256, 256, 0, stream>>>(dW_[0], dB_[0], dW_[1], dB_[1],
                                   dW_[2], dB_[2], dW_[3], dB_[3], wq);
  k_gemm<<<768, 512, 0, stream>>>(xbf, wq, qb, kb, vbt, nullptr, 0, 0);
  k_attn<<<512, 256, 0, stream>>>(qb, kb, vbt, attnb);
  k_gemm<<<256, 512, 0, stream>>>(attnb, wq, nullptr, nullptr, nullptr,
                                  out, 1, 3);
}

// Round 15
// 109.610 us; speedup vs baseline: 1.0932x; 1.0268x over previous
//
#include <hip/hip_runtime.h>

// ---------------------------------------------------------------------------
// SelfAttention with QA-LoRA quantized projections, MI355X (gfx950)
// Round 15: attn QBLK=256 (512 threads, 8 waves, grid 256 = 1 block/CU):
//           K/V staged ONCE per CU (was twice) — staging issues, LDS writes,
//           and L2/HBM K/V traffic halve. Same 4-deep single-barrier rotation
//           (per-wave vmcnt 4/3/1/0). Prep kernels fused into one launch.
//           GEMMs identical to round 12/14.
// ---------------------------------------------------------------------------

typedef __bf16 bf16x8 __attribute__((ext_vector_type(8)));
typedef float f32x4 __attribute__((ext_vector_type(4)));

#define MFMA(a, b, c) __builtin_amdgcn_mfma_f32_16x16x32_bf16(a, b, c, 0, 0, 0)

#define KEXT 1088   // 1024 + 64 extension cols (16 LoRA + 48 zeros)

__device__ __forceinline__ void gld16(const void* g, void* l) {
  __builtin_amdgcn_global_load_lds(
      (const __attribute__((address_space(1))) void*)g,
      (__attribute__((address_space(3))) void*)l, 16, 0, 0);
}

// fake_quantize: returns the clipped, round-half-even INTEGER (not dequantized).
__device__ __forceinline__ float fq(float v) {
  float q = rintf(v / 0.1f);           // v_rndne_f32: round half to even
  return fminf(fmaxf(q, -128.f), 127.f);
}

__device__ __forceinline__ float redsum16(float v) {
  v += __shfl_xor(v, 1);
  v += __shfl_xor(v, 2);
  v += __shfl_xor(v, 4);
  v += __shfl_xor(v, 8);
  return v;
}

// ---------------- fused prep kernel ----------------
// blocks 0..4095: weights -> bf16 int codes (stride-1088)
// blocks 4096..8191: x -> bf16 + ext-col group means
// blocks 8192..8447: LoRA delta -> ext cols of wq
__global__ __launch_bounds__(256) void k_prep(
    const float* __restrict__ x,
    const float* __restrict__ w0, const float* __restrict__ w1,
    const float* __restrict__ w2, const float* __restrict__ w3,
    const float* __restrict__ dW0, const float* __restrict__ dB0,
    const float* __restrict__ dW1, const float* __restrict__ dB1,
    const float* __restrict__ dW2, const float* __restrict__ dB2,
    const float* __restrict__ dW3, const float* __restrict__ dB3,
    __bf16* __restrict__ wq, __bf16* __restrict__ xbf) {
  int blk = blockIdx.x, t = threadIdx.x;
  if (blk < 4096) {
    int i = blk * 256 + t;
    int layer = i >> 18, rest = i & 262143;
    int o = rest >> 8, c4 = rest & 255;
    const float* src = (layer == 0) ? w0 : (layer == 1) ? w1 : (layer == 2) ? w2 : w3;
    float4 v = ((const float4*)src)[rest];
    __bf16 r[4] = {(__bf16)fq(v.x), (__bf16)fq(v.y), (__bf16)fq(v.z), (__bf16)fq(v.w)};
    *(uint2*)(wq + (size_t)((layer << 10) | o) * KEXT + (c4 << 2)) = *(uint2*)r;
  } else if (blk < 8192) {
    int row = blk - 4096;
    float4 v = ((const float4*)(x + (size_t)row * 1024))[t];
    __bf16 r[4] = {(__bf16)v.x, (__bf16)v.y, (__bf16)v.z, (__bf16)v.w};
    *(uint2*)(xbf + (size_t)row * KEXT + 4 * t) = *(uint2*)r;
    float s = v.x + v.y + v.z + v.w;
    s = redsum16(s);
    int g = t >> 4, j = t & 15;
    __bf16* ext = xbf + (size_t)row * KEXT + 1024;
    if (j == 0) ext[g] = (__bf16)(s * (1.f / 64.f));
    else if (j < 4) ext[16 + g * 3 + (j - 1)] = (__bf16)0.f;
  } else {
    int i = (blk - 8192) * 256 + t;
    int layer = i >> 14, o = (i >> 4) & 1023, g = i & 15;
    const float* dW = (layer == 0) ? dW0 : (layer == 1) ? dW1 : (layer == 2) ? dW2 : dW3;
    const float* dB = (layer == 0) ? dB0 : (layer == 1) ? dB1 : (layer == 2) ? dB2 : dB3;
    float acc = 0.f;
#pragma unroll
    for (int r = 0; r < 32; ++r)
      acc += (0.1f * fq(dB[o * 32 + r])) * (0.1f * fq(dW[r * 16 + g]));
    __bf16* ext = wq + (size_t)((layer << 10) | o) * KEXT + 1024;
    ext[g] = (__bf16)(20.f * acc);
#pragma unroll
    for (int k = 0; k < 3; ++k) ext[16 + g * 3 + k] = (__bf16)0.f;
  }
}

// ---------------- GEMM (8-wave, counted-vmcnt dbuf + swizzle + K-ext + T1) --
// Identical to round 12.
__global__ __launch_bounds__(512) void k_gemm(
    const __bf16* __restrict__ A,       // [4096][1088]
    const __bf16* __restrict__ Wq,      // [4][1024][1088]
    __bf16* __restrict__ qout,          // [bh][n][64]
    __bf16* __restrict__ kout,          // [bh][n][64]
    __bf16* __restrict__ vout,          // [bh][64][n] (sigma-permuted n)
    float* __restrict__ fout,           // [4096][1024]
    int mode, int layer_base) {
  __shared__ __align__(16) __bf16 lA[2][128 * 64];
  __shared__ __align__(16) __bf16 lB[2][128 * 64];

  const int t = threadIdx.x;           // 0..511
  const int lane = t & 63;
  const int wv = t >> 6;               // 0..7

  int bm, bn, z;
  {
    int xcd = blockIdx.x & 7, local = blockIdx.x >> 3;
    if (mode == 0) {                     // 768 blocks: local 0..95 = 8bm x 12zn
      int bm_l = local / 12, zn_l = local - bm_l * 12;
      bm = ((xcd >> 1) << 3) + bm_l;
      int zn = (xcd & 1) * 12 + zn_l;
      z = zn >> 3;
      bn = zn & 7;
    } else {                             // 256 blocks: local 0..31 = 8bm x 4bn
      int bm_l = local >> 2, bn_l = local & 3;
      bm = ((xcd >> 1) << 3) + bm_l;
      bn = (xcd & 1) * 4 + bn_l;
      z = 0;
    }
  }
  const int layer = layer_base + z;
  const __bf16* Wl = Wq + (size_t)layer * 1024 * KEXT;
  const int wm = wv >> 2, wn = wv & 3;   // 2 x 4 wave grid
  const int fr = lane & 15, fq4 = lane >> 4;

  const int tr = t >> 3;                      // 0..63
  const int scol = ((t & 7) ^ (tr & 7)) * 8;

  f32x4 acc[4][2];
#pragma unroll
  for (int mi = 0; mi < 4; ++mi)
#pragma unroll
    for (int ni = 0; ni < 2; ++ni) { f32x4 zz = {0.f, 0.f, 0.f, 0.f}; acc[mi][ni] = zz; }

#define STAGE(kt, buf)                                                         \
  {                                                                            \
    _Pragma("unroll") for (int i = 0; i < 2; ++i) {                            \
      int row = i * 64 + tr;                                                   \
      gld16(A + (size_t)(bm * 128 + row) * KEXT + (kt)*64 + scol,              \
            (char*)lA[buf] + (i * 512 + wv * 64) * 16);                        \
      gld16(Wl + (size_t)(bn * 128 + row) * KEXT + (kt)*64 + scol,             \
            (char*)lB[buf] + (i * 512 + wv * 64) * 16);                        \
    }                                                                          \
  }
#define KCOMPUTE(CUR)                                                          \
  {                                                                            \
    _Pragma("unroll") for (int kk = 0; kk < 2; ++kk) {                         \
      bf16x8 af[4], bfr[2];                                                    \
      _Pragma("unroll") for (int mi = 0; mi < 4; ++mi)                         \
        af[mi] = *(const bf16x8*)&lA[CUR][(wm * 64 + mi * 16 + fr) * 64 +      \
                                          (((kk << 2) | fq4) ^ (fr & 7)) * 8]; \
      _Pragma("unroll") for (int ni = 0; ni < 2; ++ni)                         \
        bfr[ni] = *(const bf16x8*)&lB[CUR][(wn * 32 + ni * 16 + fr) * 64 +     \
                                           (((kk << 2) | fq4) ^ (fr & 7)) * 8];\
      _Pragma("unroll") for (int mi = 0; mi < 4; ++mi)                         \
        _Pragma("unroll") for (int ni = 0; ni < 2; ++ni)                       \
            acc[mi][ni] = MFMA(af[mi], bfr[ni], acc[mi][ni]);                  \
    }                                                                          \
  }

  STAGE(0, 0);
  int cur = 0;
  for (int kt = 0; kt < 16; ++kt) {
    STAGE(kt + 1, cur ^ 1);
    asm volatile("s_waitcnt vmcnt(4)" ::: "memory");
    __builtin_amdgcn_s_barrier();
    __builtin_amdgcn_sched_barrier(0);
    __builtin_amdgcn_s_setprio(1);
    KCOMPUTE(cur);
    __builtin_amdgcn_s_setprio(0);
    __builtin_amdgcn_sched_barrier(0);
    __builtin_amdgcn_s_barrier();
    cur ^= 1;
  }
  asm volatile("s_waitcnt vmcnt(0)" ::: "memory");
  __builtin_amdgcn_s_barrier();
  __builtin_amdgcn_sched_barrier(0);
  KCOMPUTE(cur);
  __syncthreads();
#undef STAGE
#undef KCOMPUTE

  const float outmul =
      (mode == 0 && z == 0) ? 0.1f * 0.125f * 1.4426950408889634f : 0.1f;

  if (mode == 0 && z == 2) {
    __bf16* lw = ((__bf16*)lA) + wv * 2048;   // 4KB wave-private
#pragma unroll
    for (int mi = 0; mi < 4; ++mi) {
      int cc = mi * 2 + (fq4 >> 1), qq = fq4 & 1;
      int sb = (((cc & 4) | (qq << 1) | (cc & 1)) << 3) | ((cc & 2) << 1);
      int lc = sb >> 3, half = (sb >> 2) & 1;
#pragma unroll
      for (int ni = 0; ni < 2; ++ni) {
        int dl = ni * 16 + fr;
        __bf16 pk[4];
#pragma unroll
        for (int j = 0; j < 4; ++j) pk[j] = (__bf16)(acc[mi][ni][j] * outmul);
        *(uint2*)&lw[dl * 64 + ((lc ^ (dl & 7)) << 3) + half * 4] = *(uint2*)pk;
      }
    }
    int dl = lane >> 1, c0 = (lane & 1) * 4;
    int m0 = bm * 128 + wm * 64;
    int b = m0 >> 11, n0 = m0 & 2047;
    int h = bn * 2 + (wn >> 1);
    int dg = (wn & 1) * 32 + dl;
    __bf16* vrow = vout + ((size_t)(b * 16 + h) * 64 + dg) * 2048 + n0;
#pragma unroll
    for (int lc2 = 0; lc2 < 4; ++lc2) {
      int c = c0 + lc2;
      uint4 val = *(uint4*)&lw[dl * 64 + ((c ^ (dl & 7)) << 3)];
      *(uint4*)(vrow + c * 8) = val;
    }
  } else {
#pragma unroll
    for (int mi = 0; mi < 4; ++mi)
#pragma unroll
      for (int ni = 0; ni < 2; ++ni) {
        int o = bn * 128 + wn * 32 + ni * 16 + fr;
#pragma unroll
        for (int j = 0; j < 4; ++j) {
          int m = bm * 128 + wm * 64 + mi * 16 + fq4 * 4 + j;
          float v = acc[mi][ni][j] * outmul;
          if (mode == 0) {
            int b = m >> 11, nr = m & 2047;
            int h = o >> 6, d = o & 63;
            if (z == 0)
              qout[((size_t)(b * 16 + h) * 2048 + nr) * 64 + d] = (__bf16)v;
            else
              kout[((size_t)(b * 16 + h) * 2048 + nr) * 64 + d] = (__bf16)v;
          } else {
            fout[(size_t)m * 1024 + o] = v;
          }
        }
      }
  }
}

// ---------------- flash attention (round 15: QBLK=256, 8 waves) -------------
// Grid 256 = 1 block/CU: K/V staged once per CU. 4-deep rotation, one
// barrier/tile; per-wave staging = 1 gld16 per SK/SV (512 threads cover a
// full 64x64 tile). Steady-state vmcnt(4) keeps 2 tiles in flight.
__global__ __launch_bounds__(512) void k_attn(
    const __bf16* __restrict__ qb,   // [bh][n][64] (pre-scaled, log2 domain)
    const __bf16* __restrict__ kb,   // [bh][n][64]
    const __bf16* __restrict__ vbt,  // [bh][64][n] (sigma-permuted n)
    __bf16* __restrict__ attnb) {    // [4096][1088] (ext cols = head means)
  __shared__ __align__(16) __bf16 lK[4][64 * 64];
  __shared__ __align__(16) __bf16 lVT[4][64 * 64];

  const int t = threadIdx.x, lane = t & 63, wv = t >> 6;   // wv 0..7
  // T1: XCD rect = 4bh x 8qt
  const int xcd = blockIdx.x & 7, local = blockIdx.x >> 3;   // local 0..31
  const int bh = xcd * 4 + (local >> 3);
  const int qt = local & 7;                    // 0..7 (256 q-rows per block)
  const int fr = lane & 15, g = lane >> 4;
  const int qrow0 = qt * 256 + wv * 16;
  const size_t hbase = (size_t)bh * 2048 * 64;

  // staging: thread t covers 16B chunk t of a 64x64 tile (row t>>3)
  const int srow0 = t >> 3, sc0 = (t & 7) ^ (srow0 & 7);
  const int dst0 = (wv * 64) * 16;             // wave-uniform; HW adds lane*16

  bf16x8 qf[2][2];
#pragma unroll
  for (int s = 0; s < 2; ++s)
#pragma unroll
    for (int kk = 0; kk < 2; ++kk)
      qf[s][kk] = *(const bf16x8*)(qb + hbase + (size_t)(qrow0 + s * 128 + fr) * 64 +
                                   kk * 32 + g * 8);

  bf16x8 vones;
#pragma unroll
  for (int e = 0; e < 8; ++e) vones[e] = (__bf16)1.0f;

  f32x4 o[2][4], o4[2];
#pragma unroll
  for (int s = 0; s < 2; ++s) {
#pragma unroll
    for (int di = 0; di < 4; ++di) { f32x4 zz = {0.f, 0.f, 0.f, 0.f}; o[s][di] = zz; }
    f32x4 zz = {0.f, 0.f, 0.f, 0.f};
    o4[s] = zz;
  }

  f32x4 smA[2][4], smB[2][4];

#define SK_STAGE(KT, BUF)                                                      \
  gld16(kb + hbase + (size_t)((KT)*64 + srow0) * 64 + sc0 * 8, (char*)(BUF) + dst0);
#define SV_STAGE(KT, BUF)                                                      \
  gld16(vbt + hbase + (size_t)srow0 * 2048 + (KT)*64 + sc0 * 8, (char*)(BUF) + dst0);
#define QK_STEP(KBUF, SM)                                                      \
  {                                                                            \
    _Pragma("unroll") for (int ni = 0; ni < 4; ++ni) {                         \
      f32x4 zz = {0.f, 0.f, 0.f, 0.f};                                         \
      SM[0][ni] = zz;                                                          \
      SM[1][ni] = zz;                                                          \
    }                                                                          \
    _Pragma("unroll") for (int kk = 0; kk < 2; ++kk)                           \
        _Pragma("unroll") for (int ni = 0; ni < 4; ++ni) {                     \
      bf16x8 kf = *(const bf16x8*)&(KBUF)[(ni * 16 + fr) * 64 +                \
                                          (((kk << 2) | g) ^ (fr & 7)) * 8];   \
      SM[0][ni] = MFMA(kf, qf[0][kk], SM[0][ni]);                              \
      SM[1][ni] = MFMA(kf, qf[1][kk], SM[1][ni]);                              \
    }                                                                          \
  }
#define EXPPV_STEP(SM, VBUF)                                                   \
  {                                                                            \
    bf16x8 pa[2][2];                                                           \
    _Pragma("unroll") for (int s2 = 0; s2 < 2; ++s2)                           \
        _Pragma("unroll") for (int kk = 0; kk < 2; ++kk)                       \
            _Pragma("unroll") for (int e = 0; e < 8; ++e)                      \
                pa[s2][kk][e] = (__bf16)__builtin_amdgcn_exp2f(                \
                    SM[s2][2 * kk + (e >> 2)][e & 3]);                         \
    _Pragma("unroll") for (int kk = 0; kk < 2; ++kk) {                         \
      const int ncr = ((kk << 2) | ((g & 1) << 1) | (g >> 1)) ^ (fr & 7);      \
      _Pragma("unroll") for (int di = 0; di < 4; ++di) {                       \
        bf16x8 vf = *(const bf16x8*)&(VBUF)[(di * 16 + fr) * 64 + ncr * 8];    \
        o[0][di] = MFMA(pa[0][kk], vf, o[0][di]);                              \
        o[1][di] = MFMA(pa[1][kk], vf, o[1][di]);                              \
      }                                                                        \
      o4[0] = MFMA(pa[0][kk], vones, o4[0]);                                   \
      o4[1] = MFMA(pa[1][kk], vones, o4[1]);                                   \
    }                                                                          \
  }
#define WAITBAR(N)                                                             \
  asm volatile("s_waitcnt vmcnt(" #N ")" ::: "memory");                        \
  __builtin_amdgcn_s_barrier();                                                \
  __builtin_amdgcn_sched_barrier(0);

  // prologue: K(0)->lK[0], K(1)->lK[1], V(0)->lVT[0]  (3 loads/wave in flight)
  SK_STAGE(0, lK[0]);
  SK_STAGE(1, lK[1]);
  SV_STAGE(0, lVT[0]);

  // --- tile 0 (no EXPPV) ---
  SK_STAGE(2, lK[2]);
  SV_STAGE(1, lVT[1]);
  WAITBAR(4)                         // K(0) complete
  __builtin_amdgcn_s_setprio(1);
  QK_STEP(lK[0], smB);
  __builtin_amdgcn_s_setprio(0);

  // --- tiles 1..3 ---
  SK_STAGE(3, lK[3]);
  SV_STAGE(2, lVT[2]);
  WAITBAR(4)
  __builtin_amdgcn_s_setprio(1);
  QK_STEP(lK[1], smA);
  EXPPV_STEP(smB, lVT[0]);
  __builtin_amdgcn_s_setprio(0);

  SK_STAGE(4, lK[0]);
  SV_STAGE(3, lVT[3]);
  WAITBAR(4)
  __builtin_amdgcn_s_setprio(1);
  QK_STEP(lK[2], smB);
  EXPPV_STEP(smA, lVT[1]);
  __builtin_amdgcn_s_setprio(0);

  SK_STAGE(5, lK[1]);
  SV_STAGE(4, lVT[0]);
  WAITBAR(4)
  __builtin_amdgcn_s_setprio(1);
  QK_STEP(lK[3], smA);
  EXPPV_STEP(smB, lVT[2]);
  __builtin_amdgcn_s_setprio(0);

  // --- tiles 4..27: six 4-tile groups, fixed buffer pattern ---
  for (int gidx = 0; gidx < 6; ++gidx) {
    int t0 = 4 + gidx * 4;
    SK_STAGE(t0 + 2, lK[2]);
    SV_STAGE(t0 + 1, lVT[1]);
    WAITBAR(4)
    __builtin_amdgcn_s_setprio(1);
    QK_STEP(lK[0], smB);
    EXPPV_STEP(smA, lVT[3]);
    __builtin_amdgcn_s_setprio(0);

    SK_STAGE(t0 + 3, lK[3]);
    SV_STAGE(t0 + 2, lVT[2]);
    WAITBAR(4)
    __builtin_amdgcn_s_setprio(1);
    QK_STEP(lK[1], smA);
    EXPPV_STEP(smB, lVT[0]);
    __builtin_amdgcn_s_setprio(0);

    SK_STAGE(t0 + 4, lK[0]);
    SV_STAGE(t0 + 3, lVT[3]);
    WAITBAR(4)
    __builtin_amdgcn_s_setprio(1);
    QK_STEP(lK[2], smB);
    EXPPV_STEP(smA, lVT[1]);
    __builtin_amdgcn_s_setprio(0);

    SK_STAGE(t0 + 5, lK[1]);
    SV_STAGE(t0 + 4, lVT[0]);
    WAITBAR(4)
    __builtin_amdgcn_s_setprio(1);
    QK_STEP(lK[3], smA);
    EXPPV_STEP(smB, lVT[2]);
    __builtin_amdgcn_s_setprio(0);
  }

  // --- peeled tail: tiles 28..31 ---
  SK_STAGE(30, lK[2]);
  SV_STAGE(29, lVT[1]);
  WAITBAR(4)
  __builtin_amdgcn_s_setprio(1);
  QK_STEP(lK[0], smB);
  EXPPV_STEP(smA, lVT[3]);
  __builtin_amdgcn_s_setprio(0);

  SK_STAGE(31, lK[3]);
  SV_STAGE(30, lVT[2]);
  WAITBAR(4)
  __builtin_amdgcn_s_setprio(1);
  QK_STEP(lK[1], smA);
  EXPPV_STEP(smB, lVT[0]);
  __builtin_amdgcn_s_setprio(0);

  // t=30 (no SK; newer-than-{K(30),V(29)}: SK31,SV30,SV31 = 3)
  SV_STAGE(31, lVT[3]);
  WAITBAR(3)
  __builtin_amdgcn_s_setprio(1);
  QK_STEP(lK[2], smB);
  EXPPV_STEP(smA, lVT[1]);
  __builtin_amdgcn_s_setprio(0);

  // t=31 (no issues; newer-than-{K(31),V(30)}: SV31 = 1)
  WAITBAR(1)
  __builtin_amdgcn_s_setprio(1);
  QK_STEP(lK[3], smA);
  EXPPV_STEP(smB, lVT[2]);
  __builtin_amdgcn_s_setprio(0);

  // final: V(31)
  WAITBAR(0)
  EXPPV_STEP(smA, lVT[3]);

#undef SK_STAGE
#undef SV_STAGE
#undef QK_STEP
#undef EXPPV_STEP
#undef WAITBAR

  // epilogue: normalize, write attn bf16 into stride-1088 rows + ext cols
  const int b = bh >> 4, h = bh & 15;
#pragma unroll
  for (int s = 0; s < 2; ++s)
#pragma unroll
    for (int j = 0; j < 4; ++j) {
      float inv = 1.f / o4[s][j];
      int nr = qt * 256 + s * 128 + wv * 16 + g * 4 + j;
      size_t rowbase = (size_t)(b * 2048 + nr) * KEXT;
      float rowsum = 0.f;
#pragma unroll
      for (int di = 0; di < 4; ++di) {
        float vv = o[s][di][j] * inv;
        attnb[rowbase + h * 64 + di * 16 + fr] = (__bf16)vv;
        rowsum += vv;
      }
      rowsum = redsum16(rowsum);
      if (fr == 0) attnb[rowbase + 1024 + h] = (__bf16)(rowsum * (1.f / 64.f));
      if (h < 3) attnb[rowbase + 1040 + h * 16 + fr] = (__bf16)0.f;  // zero pad
    }
}

// ---------------- launch ----------------
extern "C" void kernel_launch(void* const* d_in, const int* in_sizes, int n_in,
                              void* d_out, int out_size, void* d_ws, size_t ws_size,
                              hipStream_t stream) {
  const float* x = (const float*)d_in[0];
  float* out = (float*)d_out;

  char* ws = (char*)d_ws;
  const size_t MB = 1ull << 20;
  __bf16* xbf   = (__bf16*)(ws);                 // 4096*1088*2 = 8.9 MB
  __bf16* attnb = xbf;                           // alias: xbf dead after QKV GEMM
  __bf16* wq    = (__bf16*)(ws + 9 * MB);        // 4*1024*1088*2 = 8.9 MB
  __bf16* qb    = (__bf16*)(ws + 18 * MB);       // 8 MB
  __bf16* kb    = (__bf16*)(ws + 26 * MB);       // 8 MB
  __bf16* vbt   = (__bf16*)(ws + 34 * MB);       // 8 MB -> ends 42 MB

  k_prep<<<8448, 256, 0, stream>>>(
      x, (const float*)d_in[1], (const float*)d_in[4], (const float*)d_in[7],
      (const float*)d_in[10], (const float*)d_in[2], (const float*)d_in[3],
      (const float*)d_in[5], (const float*)d_in[6], (const float*)d_in[8],
      (const float*)d_in[9], (const float*)d_in[11], (const float*)d_in[12],
      wq, xbf);
  k_gemm<<<768, 512, 0, stream>>>(xbf, wq, qb, kb, vbt, nullptr, 0, 0);
  k_attn<<<256, 512, 0, stream>>>(qb, kb, vbt, attnb);
  k_gemm<<<256, 512, 0, stream>>>(attnb, wq, nullptr, nullptr, nullptr,
                                  out, 1, 3);
}